// Round 10
// baseline (417.337 us; speedup 1.0000x reference)
//
#include <hip/hip_runtime.h>
#include <math.h>

#define N_INPC 3
#define N_HID 64
#define N_OUTC 10
#define SEQ_LEN 8
#define N_ROLL 16
#define DT 0.042f
#define GAMMA 2.7f
#define EPSC 4.7f
#define HH 12
#define WW 10
#define NPIX 120
#define BATCH 16
#define NC 128
#define NK 1152

typedef __attribute__((ext_vector_type(8))) short short8;
typedef __attribute__((ext_vector_type(4))) float f32x4;
typedef unsigned short ushort_t;
typedef unsigned long long u64;

__device__ __forceinline__ ushort_t f2bf(float v) {
  union { float f; unsigned u; } x; x.f = v;
  unsigned r = x.u + 0x7fff + ((x.u >> 16) & 1);  // round-nearest-even
  return (ushort_t)(r >> 16);
}

// ---------------------------------------------------------------------------
// Single fused persistent kernel. 120 WGs (one per pixel) x 256 threads
// (4 waves; wave wv owns o-tile [wv*16, wv*16+16) with the FULL K=1152).
//
//  prologue: weights pw_w -> bf16 B-fragments DIRECTLY in registers (36 frags,
//            144 VGPR); readin conv (fp32) -> state regs + publish S_0.
//  loop:     per-wave spin on 8 neighbor flags (relaxed AGENT atomics, proven
//            R6) -> compiler fence -> A-frags straight global->VGPR (the MFMA
//            A layout [lane=(kg,b): 8 consecutive k'] IS 16 contiguous bytes
//            of Sg[pix][b][c]) -> 36 MFMA -> tanh update (wave-local) ->
//            tmp -> publish u64 -> drain -> flag.  2 barriers per step.
//  epilogue: readout from in-register hy -> d_out.
//
// Sync protocol (R6-proven): all cross-WG traffic via RELAXED agent-scope
// atomics (per-op at L3 coherence point, no acquire/release L2 storms);
// ordering from the vmcnt(0) drain __syncthreads performs before s_barrier,
// plus explicit zero-cost compiler fences after each spin so the relaxed
// A-loads cannot be hoisted above the spin exit. flag[p] = v <=> "pixel p's
// S_v is visible at L3". Ping-pong WAR safe: writer of S_{s+1} first observed
// all 8 neighbor flags >= s, certifying their reads of S_{s-1} (the buffer
// being overwritten) completed. Flags start 0xAAAAAAAA (poison) = negative.
__global__ __launch_bounds__(256, 1) void persist7_kernel(
    ushort_t* __restrict__ SgA, ushort_t* __restrict__ SgB,
    const float* __restrict__ x, const float* __restrict__ rw,
    const float* __restrict__ rb, const float* __restrict__ pw_w,
    const float* __restrict__ pwb, const float* __restrict__ row,
    const float* __restrict__ rob, float* __restrict__ out,
    int* __restrict__ flags) {
  __shared__ float Sf[16][128];      // readin staging (8 KB)
  __shared__ ushort_t tmp[16][128];  // bf16 publish staging (4 KB)
  __shared__ float hyf[16][64];      // readout staging (4 KB)

  const int p = blockIdx.x;
  const int ph = p / WW, pw_ = p % WW;
  const int tid = threadIdx.x, wv = tid >> 6, l = tid & 63;
  const int kg = l >> 4, c16 = l & 15;
  const int o_g = wv * 16 + c16;     // this wave's output channel
  const int b0 = kg * 4;             // this lane's batch quad (C rows)

  // ---- spin metadata: lanes 0..7 watch the 8 neighbors
  bool rel = false;
  int fadd = 0;
  if (l < 8) {
    const int q = l + (l >= 4);      // skip center
    const int nh = ph + q / 3 - 1, nw = pw_ + q % 3 - 1;
    if ((unsigned)nh < (unsigned)HH && (unsigned)nw < (unsigned)WW) {
      rel = true;
      fadd = (nh * WW + nw) * 16;    // 64B-padded flags
    }
  }

  // ================= weights -> registers (transpose on the fly) ===========
  // breg[ks] lane (kg,c16=o): 8 bf16 for k' = ks*32 + kg*8 + j,
  // k' = ij*128 + c  (ij = neighbor tap, c = state channel).
  short8 breg[36];
#pragma unroll
  for (int ks = 0; ks < 36; ++ks) {
    union { ushort_t us[8]; short8 s8; } pk;
#pragma unroll
    for (int j = 0; j < 8; ++j) {
      const int kp = ks * 32 + kg * 8 + j;
      const int ij = kp >> 7, c = kp & 127;
      pk.us[j] = f2bf(pw_w[((size_t)o_g * NK + c * 9 + ij) * NPIX + p]);
    }
    breg[ks] = pk.s8;
  }
  const float pb = pwb[o_g * NPIX + p];

  // ================= readin conv (fp32, EDGE pad), own pixel ===============
  {
    const int c = tid & 127;                    // state channel
    const int bh = tid >> 7;                    // batch octet 0..1
    const int oc = (c < 64) ? (64 + c) : (c - 64);
    int ihs[3], iws[3];
#pragma unroll
    for (int d = 0; d < 3; ++d) {
      int ih = ph + d - 1; ihs[d] = ih < 0 ? 0 : (ih > HH - 1 ? HH - 1 : ih);
      int iw = pw_ + d - 1; iws[d] = iw < 0 ? 0 : (iw > WW - 1 ? WW - 1 : iw);
    }
    float a8[8];
#pragma unroll
    for (int j = 0; j < 8; ++j) a8[j] = rb[oc];
    for (int ch = 0; ch < SEQ_LEN * N_INPC; ++ch) {
      const int tt = ch / N_INPC, ic = ch % N_INPC;
      const float* wb = rw + (oc * (SEQ_LEN * N_INPC) + ch) * 9;
      float w9[9];
#pragma unroll
      for (int t2 = 0; t2 < 9; ++t2) w9[t2] = wb[t2];
#pragma unroll
      for (int j = 0; j < 8; ++j) {
        const float* xb =
            x + (((size_t)(tt * BATCH + bh * 8 + j) * N_INPC + ic) * HH) * WW;
        float s = 0.f;
#pragma unroll
        for (int di = 0; di < 3; ++di)
#pragma unroll
          for (int dj = 0; dj < 3; ++dj)
            s += xb[ihs[di] * WW + iws[dj]] * w9[di * 3 + dj];
        a8[j] += s;
      }
    }
#pragma unroll
    for (int j = 0; j < 8; ++j) Sf[bh * 8 + j][c] = a8[j];
  }
  __syncthreads();

  // ---- every wave is an owner: fp32 master state -> regs, bf16 -> tmp
  float hzr[4], hyr[4];
#pragma unroll
  for (int r = 0; r < 4; ++r) {
    hzr[r] = Sf[b0 + r][o_g];
    hyr[r] = Sf[b0 + r][64 + o_g];
    tmp[b0 + r][o_g] = f2bf(hzr[r]);
    tmp[b0 + r][64 + o_g] = f2bf(hyr[r]);
  }
  __syncthreads();

  // ---- publish S_0 + flag 0
  {
    const int b = tid >> 4, m = tid & 15;       // 2 u64 = 16B per thread
    union { ushort_t us[8]; u64 u2[2]; } pk;
#pragma unroll
    for (int j = 0; j < 8; ++j) pk.us[j] = tmp[b][m * 8 + j];
    u64* dst = (u64*)(SgA + ((size_t)(p * BATCH + b)) * NC + m * 8);
    __hip_atomic_store(dst, pk.u2[0], __ATOMIC_RELAXED, __HIP_MEMORY_SCOPE_AGENT);
    __hip_atomic_store(dst + 1, pk.u2[1], __ATOMIC_RELAXED, __HIP_MEMORY_SCOPE_AGENT);
  }
  __syncthreads();  // vmcnt(0) drained -> S_0 at L3
  if (tid == 0)
    __hip_atomic_store(flags + p * 16, 0, __ATOMIC_RELAXED,
                       __HIP_MEMORY_SCOPE_AGENT);

  // ================= rollout =================
  for (int s = 0; s < N_ROLL; ++s) {
    const ushort_t* __restrict__ sgc = (s & 1) ? SgB : SgA;
    ushort_t* __restrict__ sgn = (s & 1) ? SgA : SgB;

    // ---- per-wave spin: 8 neighbor flags >= s (no block barrier needed)
    while (true) {
      int f = 0x7fffffff;
      if (rel)
        f = __hip_atomic_load(flags + fadd, __ATOMIC_RELAXED,
                              __HIP_MEMORY_SCOPE_AGENT);
      if (__all(!rel || f >= s)) break;
      __builtin_amdgcn_s_sleep(1);
    }
    asm volatile("" ::: "memory");  // forbid hoisting A-loads above the spin

    // ---- A-frags straight from global + 36 MFMA (4 acc chains)
    f32x4 ac0 = {0.f, 0.f, 0.f, 0.f}, ac1 = {0.f, 0.f, 0.f, 0.f};
    f32x4 ac2 = {0.f, 0.f, 0.f, 0.f}, ac3 = {0.f, 0.f, 0.f, 0.f};
#pragma unroll
    for (int ks = 0; ks < 36; ++ks) {
      const int q = ks >> 2;                    // neighbor tap (uniform)
      const int nh = ph + q / 3 - 1, nw = pw_ + q % 3 - 1;
      short8 av = {0, 0, 0, 0, 0, 0, 0, 0};
      if ((unsigned)nh < (unsigned)HH && (unsigned)nw < (unsigned)WW) {
        const u64* src = (const u64*)(sgc +
            (size_t)(nh * WW + nw) * (BATCH * NC) + c16 * NC +
            ((ks & 3) * 32 + kg * 8));
        union { u64 u[2]; short8 s8; } cv;
        cv.u[0] = __hip_atomic_load(src, __ATOMIC_RELAXED,
                                    __HIP_MEMORY_SCOPE_AGENT);
        cv.u[1] = __hip_atomic_load(src + 1, __ATOMIC_RELAXED,
                                    __HIP_MEMORY_SCOPE_AGENT);
        av = cv.s8;
      }
      switch (ks & 3) {
        case 0: ac0 = __builtin_amdgcn_mfma_f32_16x16x32_bf16(av, breg[ks], ac0, 0, 0, 0); break;
        case 1: ac1 = __builtin_amdgcn_mfma_f32_16x16x32_bf16(av, breg[ks], ac1, 0, 0, 0); break;
        case 2: ac2 = __builtin_amdgcn_mfma_f32_16x16x32_bf16(av, breg[ks], ac2, 0, 0, 0); break;
        default: ac3 = __builtin_amdgcn_mfma_f32_16x16x32_bf16(av, breg[ks], ac3, 0, 0, 0); break;
      }
    }
    f32x4 acc = (ac0 + ac1) + (ac2 + ac3);

    // ---- fused tanh state update (wave-local, no cross-wave reduce)
#pragma unroll
    for (int r = 0; r < 4; ++r) {
      const float pre = acc[r] + pb;
      const float hz = hzr[r], hy = hyr[r];
      const float hzn = hz + DT * (tanhf(pre) - GAMMA * hy - EPSC * hz);
      const float hyn = hy + DT * hzn;
      hzr[r] = hzn;
      hyr[r] = hyn;
      if (s < N_ROLL - 1) {
        tmp[b0 + r][o_g] = f2bf(hzn);
        tmp[b0 + r][64 + o_g] = f2bf(hyn);
      }
    }

    if (s < N_ROLL - 1) {
      __syncthreads();  // B1: tmp complete
      {
        const int b = tid >> 4, m = tid & 15;
        union { ushort_t us[8]; u64 u2[2]; } pk;
#pragma unroll
        for (int j = 0; j < 8; ++j) pk.us[j] = tmp[b][m * 8 + j];
        u64* dst = (u64*)(sgn + ((size_t)(p * BATCH + b)) * NC + m * 8);
        __hip_atomic_store(dst, pk.u2[0], __ATOMIC_RELAXED,
                           __HIP_MEMORY_SCOPE_AGENT);
        __hip_atomic_store(dst + 1, pk.u2[1], __ATOMIC_RELAXED,
                           __HIP_MEMORY_SCOPE_AGENT);
      }
      __syncthreads();  // B2: vmcnt(0) drained -> S_{s+1} at L3
      if (tid == 0)
        __hip_atomic_store(flags + p * 16, s + 1, __ATOMIC_RELAXED,
                           __HIP_MEMORY_SCOPE_AGENT);
    }
  }

  // ================= readout (own pixel) -> d_out =================
  __syncthreads();
#pragma unroll
  for (int r = 0; r < 4; ++r) hyf[b0 + r][o_g] = hyr[r];
  __syncthreads();
  if (tid < BATCH * N_OUTC) {
    const int b = tid / N_OUTC, o = tid % N_OUTC;
    float acc2 = rob[o];
#pragma unroll 8
    for (int c2 = 0; c2 < 64; ++c2) acc2 += hyf[b][c2] * row[o * 64 + c2];
    out[((size_t)(b * N_OUTC + o)) * NPIX + p] = acc2;
  }
}

// ---------------------------------------------------------------------------
extern "C" void kernel_launch(void* const* d_in, const int* in_sizes, int n_in,
                              void* d_out, int out_size, void* d_ws, size_t ws_size,
                              hipStream_t stream) {
  const float* x         = (const float*)d_in[0];
  const float* readin_w  = (const float*)d_in[1];
  const float* readin_b  = (const float*)d_in[2];
  const float* pw_w      = (const float*)d_in[3];
  const float* pw_b      = (const float*)d_in[4];
  const float* readout_w = (const float*)d_in[5];
  const float* readout_b = (const float*)d_in[6];
  float* out = (float*)d_out;

  ushort_t* Sg0 = (ushort_t*)d_ws;              // 245,760 bf16
  ushort_t* Sg1 = Sg0 + 245760;
  int*      flg = (int*)(Sg1 + 245760);         // 120 x 64B-padded flags

  ushort_t* aSgA = Sg0;
  ushort_t* aSgB = Sg1;
  const float* aX = x;
  const float* aRw = readin_w;
  const float* aRb = readin_b;
  const float* aPw = pw_w;
  const float* aPwb = pw_b;
  const float* aRow = readout_w;
  const float* aRob = readout_b;
  float* aOut = out;
  int* aFlg = flg;
  void* args[] = {(void*)&aSgA, (void*)&aSgB, (void*)&aX,  (void*)&aRw,
                  (void*)&aRb,  (void*)&aPw,  (void*)&aPwb, (void*)&aRow,
                  (void*)&aRob, (void*)&aOut, (void*)&aFlg};
  hipError_t rc = hipLaunchCooperativeKernel(
      (const void*)persist7_kernel, dim3(NPIX), dim3(256), args, 0, stream);
  if (rc != hipSuccess) {
    // Fallback: plain launch. 120 blocks of 256 thr on 256 CUs with
    // __launch_bounds__(256,1) => all blocks resident; flag protocol safe.
    persist7_kernel<<<dim3(NPIX), dim3(256), 0, stream>>>(
        aSgA, aSgB, aX, aRw, aRb, aPw, aPwb, aRow, aRob, aOut, aFlg);
  }
}